// Round 1
// baseline (327.730 us; speedup 1.0000x reference)
//
#include <hip/hip_runtime.h>
#include <stdint.h>

#define B_ 4
#define N_ 4096
#define C_ 256
#define CK_ 32
#define TQ 64
#define TK 64
#define LOG2E 1.44269504088896340736f

typedef float f32x4 __attribute__((ext_vector_type(4)));
typedef short s16x8 __attribute__((ext_vector_type(8)));
typedef __bf16 bf16x8 __attribute__((ext_vector_type(8)));

static __device__ __forceinline__ unsigned short f2bf(float f) {
    union { float f; uint32_t u; } v; v.f = f;
    return (unsigned short)((v.u + 0x7FFFu + ((v.u >> 16) & 1u)) >> 16);
}
static __device__ __forceinline__ float bf2f(unsigned short h) {
    union { uint32_t u; float f; } v; v.u = ((uint32_t)h) << 16;
    return v.f;
}
static __device__ __forceinline__ bf16x8 as_bf(s16x8 v) {
    return __builtin_bit_cast(bf16x8, v);
}

// ---------------- projection: f,g (hi/lo bf16) + h (bf16, transposed [B][C][N]) ----
// grid: B_*N_/8 blocks of 64 threads. Thread t handles concat-cols {t, t+64, t+128,
// t+192, t+256} of [f(32)|g(32)|h(256)] for 8 consecutive rows.
__global__ __launch_bounds__(64) void proj_kernel(
    const float* __restrict__ x,
    const float* __restrict__ Wf, const float* __restrict__ bfp,
    const float* __restrict__ Wg, const float* __restrict__ bgp,
    const float* __restrict__ Wh, const float* __restrict__ bhp,
    unsigned short* __restrict__ q_hi, unsigned short* __restrict__ q_lo,
    unsigned short* __restrict__ k_hi, unsigned short* __restrict__ k_lo,
    unsigned short* __restrict__ v_t)
{
    const int R = 8;
    __shared__ __align__(16) float xs[R * C_];
    const int tid = threadIdx.x;
    const int row0 = blockIdx.x * R;
    const float* xsrc = x + (size_t)row0 * C_;
    #pragma unroll
    for (int i = 0; i < (R * C_ / 4) / 64; i++)
        ((f32x4*)xs)[tid + 64 * i] = ((const f32x4*)xsrc)[tid + 64 * i];
    __syncthreads();

    // col slot 0: f (tid<32) or g (tid>=32), stride CK_; slots 1..4: h cols tid+64*i, stride C_
    const float* w0 = (tid < 32) ? (Wf + tid) : (Wg + (tid - 32));
    const float  bias0 = (tid < 32) ? bfp[tid] : bgp[tid - 32];
    const float* wh[4]; float biash[4];
    #pragma unroll
    for (int i = 0; i < 4; i++) {
        wh[i] = Wh + (tid + 64 * i);
        biash[i] = bhp[tid + 64 * i];
    }

    float acc0[R]; float acch[4][R];
    #pragma unroll
    for (int r = 0; r < R; r++) { acc0[r] = 0.f;
        #pragma unroll
        for (int i = 0; i < 4; i++) acch[i][r] = 0.f; }

    for (int k4 = 0; k4 < C_ / 4; k4++) {
        float wa[4], whv[4][4];
        #pragma unroll
        for (int q = 0; q < 4; q++) wa[q] = w0[(size_t)(k4 * 4 + q) * CK_];
        #pragma unroll
        for (int i = 0; i < 4; i++)
            #pragma unroll
            for (int q = 0; q < 4; q++) whv[i][q] = wh[i][(size_t)(k4 * 4 + q) * C_];
        #pragma unroll
        for (int r = 0; r < R; r++) {
            f32x4 xv = ((const f32x4*)xs)[r * (C_ / 4) + k4];
            acc0[r] += xv.x * wa[0] + xv.y * wa[1] + xv.z * wa[2] + xv.w * wa[3];
            #pragma unroll
            for (int i = 0; i < 4; i++)
                acch[i][r] += xv.x * whv[i][0] + xv.y * whv[i][1]
                            + xv.z * whv[i][2] + xv.w * whv[i][3];
        }
    }

    const int b = row0 / N_, n0 = row0 % N_;
    {   // f -> key arrays, g -> query arrays, hi/lo split for fp32-accurate scores
        unsigned short* hi_dst = (tid < 32) ? k_hi : q_hi;
        unsigned short* lo_dst = (tid < 32) ? k_lo : q_lo;
        const int c = (tid < 32) ? tid : tid - 32;
        #pragma unroll
        for (int r = 0; r < R; r++) {
            float v = acc0[r] + bias0;
            unsigned short hi = f2bf(v);
            unsigned short lo = f2bf(v - bf2f(hi));
            size_t o = ((size_t)(b * N_ + n0 + r)) * CK_ + c;
            hi_dst[o] = hi; lo_dst[o] = lo;
        }
    }
    #pragma unroll
    for (int i = 0; i < 4; i++) {
        union { s16x8 v; unsigned short u[8]; } pk;
        #pragma unroll
        for (int r = 0; r < R; r++) pk.u[r] = f2bf(acch[i][r] + biash[i]);
        *(s16x8*)(v_t + ((size_t)b * C_ + (tid + 64 * i)) * N_ + n0) = pk.v;
    }
}

// ---------------- flash attention + gamma*o + x epilogue ----------------
// grid (N_/TQ, B_), 256 threads = 4 waves x 16 q-rows.
__global__ __launch_bounds__(256) void attn_kernel(
    const unsigned short* __restrict__ q_hi, const unsigned short* __restrict__ q_lo,
    const unsigned short* __restrict__ k_hi, const unsigned short* __restrict__ k_lo,
    const unsigned short* __restrict__ v_t,
    const float* __restrict__ x, const float* __restrict__ gamma_p,
    float* __restrict__ out)
{
    __shared__ __align__(16) unsigned short fhi_s[TK * 40];   // keys hi, pad 32->40
    __shared__ __align__(16) unsigned short flo_s[TK * 40];   // keys lo
    __shared__ __align__(16) unsigned short hT_s[C_ * 72];    // values^T, pad 64->72
    __shared__ __align__(16) unsigned short P_s[4 * 16 * 72]; // per-wave P, pad 64->72

    const int tid  = threadIdx.x;
    const int lane = tid & 63;
    const int wave = tid >> 6;
    const int col  = lane & 15;
    const int quad = lane >> 4;
    const int qt = blockIdx.x;
    const int b  = blockIdx.y;

    // Q A-fragments: A[m=lane&15][k=quad*8+j], one frag spans full Ck=32
    const size_t qoff = ((size_t)(b * N_ + qt * TQ + wave * 16 + col)) * CK_ + quad * 8;
    const bf16x8 aQh = as_bf(*(const s16x8*)(q_hi + qoff));
    const bf16x8 aQl = as_bf(*(const s16x8*)(q_lo + qoff));

    f32x4 acc[16];
    #pragma unroll
    for (int nt = 0; nt < 16; nt++) acc[nt] = (f32x4){0.f, 0.f, 0.f, 0.f};
    float m_r[4] = {-1e30f, -1e30f, -1e30f, -1e30f};
    float l_r[4] = {0.f, 0.f, 0.f, 0.f};

    for (int kt = 0; kt < N_ / TK; kt++) {
        __syncthreads();   // previous iteration's consumers done before overwrite
        {
            // stage key tile (64x32 hi + lo): flat-contiguous, one 16B chunk/thread
            const s16x8* sh = (const s16x8*)(k_hi + ((size_t)(b * N_ + kt * TK)) * CK_);
            const s16x8* sl = (const s16x8*)(k_lo + ((size_t)(b * N_ + kt * TK)) * CK_);
            s16x8 vh = sh[tid], vl = sl[tid];
            const int fr = tid >> 2, fc = (tid & 3) * 8;
            *(s16x8*)(fhi_s + fr * 40 + fc) = vh;
            *(s16x8*)(flo_s + fr * 40 + fc) = vl;
            // stage value tile transposed: thread = channel c, 64 keys contiguous
            const s16x8* sv = (const s16x8*)(v_t + ((size_t)b * C_ + tid) * N_ + (size_t)kt * TK);
            #pragma unroll
            for (int i = 0; i < 8; i++)
                *(s16x8*)(hT_s + tid * 72 + i * 8) = sv[i];
        }
        __syncthreads();

        // S = Q K^T over 4 key sub-tiles; hi/lo split => fp32-accurate logits
        f32x4 sc[4];
        #pragma unroll
        for (int t = 0; t < 4; t++) {
            bf16x8 bh = as_bf(*(const s16x8*)(fhi_s + (t * 16 + col) * 40 + quad * 8));
            bf16x8 bl = as_bf(*(const s16x8*)(flo_s + (t * 16 + col) * 40 + quad * 8));
            f32x4 s = (f32x4){0.f, 0.f, 0.f, 0.f};
            s = __builtin_amdgcn_mfma_f32_16x16x32_bf16(aQh, bh, s, 0, 0, 0);
            s = __builtin_amdgcn_mfma_f32_16x16x32_bf16(aQl, bh, s, 0, 0, 0);
            s = __builtin_amdgcn_mfma_f32_16x16x32_bf16(aQh, bl, s, 0, 0, 0);
            sc[t] = s;
        }

        // online softmax (exp2 domain); C-layout row = quad*4+r
        float mloc[4], alpha[4], rs[4], p[4][4];
        #pragma unroll
        for (int r = 0; r < 4; r++) {
            sc[0][r] *= LOG2E; sc[1][r] *= LOG2E; sc[2][r] *= LOG2E; sc[3][r] *= LOG2E;
            mloc[r] = fmaxf(fmaxf(sc[0][r], sc[1][r]), fmaxf(sc[2][r], sc[3][r]));
        }
        #pragma unroll
        for (int off = 1; off < 16; off <<= 1)
            #pragma unroll
            for (int r = 0; r < 4; r++)
                mloc[r] = fmaxf(mloc[r], __shfl_xor(mloc[r], off, 64));
        #pragma unroll
        for (int r = 0; r < 4; r++) {
            float mn = fmaxf(m_r[r], mloc[r]);
            alpha[r] = __builtin_amdgcn_exp2f(m_r[r] - mn);
            m_r[r] = mn;
            p[0][r] = __builtin_amdgcn_exp2f(sc[0][r] - mn);
            p[1][r] = __builtin_amdgcn_exp2f(sc[1][r] - mn);
            p[2][r] = __builtin_amdgcn_exp2f(sc[2][r] - mn);
            p[3][r] = __builtin_amdgcn_exp2f(sc[3][r] - mn);
            rs[r] = (p[0][r] + p[1][r]) + (p[2][r] + p[3][r]);
        }
        #pragma unroll
        for (int off = 1; off < 16; off <<= 1)
            #pragma unroll
            for (int r = 0; r < 4; r++)
                rs[r] += __shfl_xor(rs[r], off, 64);
        #pragma unroll
        for (int r = 0; r < 4; r++)
            l_r[r] = l_r[r] * alpha[r] + rs[r];
        #pragma unroll
        for (int nt = 0; nt < 16; nt++)
            #pragma unroll
            for (int r = 0; r < 4; r++)
                acc[nt][r] *= alpha[r];

        // P: C-layout -> A-layout via per-wave LDS round trip
        unsigned short* Pw = P_s + wave * (16 * 72);
        #pragma unroll
        for (int t = 0; t < 4; t++)
            #pragma unroll
            for (int r = 0; r < 4; r++)
                Pw[(quad * 4 + r) * 72 + t * 16 + col] = f2bf(p[t][r]);
        __syncthreads();
        const bf16x8 aP0 = as_bf(*(const s16x8*)(Pw + col * 72 + quad * 8));
        const bf16x8 aP1 = as_bf(*(const s16x8*)(Pw + col * 72 + 32 + quad * 8));

        // O += P V  (B-frag: V[k][c] = hT_s[c][k], contiguous in k)
        #pragma unroll
        for (int nt = 0; nt < 16; nt++) {
            bf16x8 bv0 = as_bf(*(const s16x8*)(hT_s + (nt * 16 + col) * 72 + quad * 8));
            bf16x8 bv1 = as_bf(*(const s16x8*)(hT_s + (nt * 16 + col) * 72 + 32 + quad * 8));
            acc[nt] = __builtin_amdgcn_mfma_f32_16x16x32_bf16(aP0, bv0, acc[nt], 0, 0, 0);
            acc[nt] = __builtin_amdgcn_mfma_f32_16x16x32_bf16(aP1, bv1, acc[nt], 0, 0, 0);
        }
    }

    // epilogue: y = gamma * (O / l) + x
    const float gamma = *gamma_p;
    float rcp[4];
    #pragma unroll
    for (int r = 0; r < 4; r++) rcp[r] = 1.0f / l_r[r];
    #pragma unroll
    for (int nt = 0; nt < 16; nt++)
        #pragma unroll
        for (int r = 0; r < 4; r++) {
            size_t idx = ((size_t)(b * N_ + qt * TQ + wave * 16 + quad * 4 + r)) * C_
                       + nt * 16 + col;
            out[idx] = gamma * (acc[nt][r] * rcp[r]) + x[idx];
        }
}

extern "C" void kernel_launch(void* const* d_in, const int* in_sizes, int n_in,
                              void* d_out, int out_size, void* d_ws, size_t ws_size,
                              hipStream_t stream) {
    const float* x   = (const float*)d_in[0];
    const float* Wf  = (const float*)d_in[1];
    const float* bfp = (const float*)d_in[2];
    const float* Wg  = (const float*)d_in[3];
    const float* bgp = (const float*)d_in[4];
    const float* Wh  = (const float*)d_in[5];
    const float* bhp = (const float*)d_in[6];
    const float* gam = (const float*)d_in[7];
    float* out = (float*)d_out;

    unsigned char* ws = (unsigned char*)d_ws;
    const size_t MB = 1 << 20;
    unsigned short* q_hi = (unsigned short*)(ws + 0 * MB);  // [B][N][32] bf16 bits
    unsigned short* q_lo = (unsigned short*)(ws + 1 * MB);
    unsigned short* k_hi = (unsigned short*)(ws + 2 * MB);
    unsigned short* k_lo = (unsigned short*)(ws + 3 * MB);
    unsigned short* v_t  = (unsigned short*)(ws + 4 * MB);  // [B][C][N] bf16 bits, 8 MB

    proj_kernel<<<dim3(B_ * N_ / 8), dim3(64), 0, stream>>>(
        x, Wf, bfp, Wg, bgp, Wh, bhp, q_hi, q_lo, k_hi, k_lo, v_t);
    attn_kernel<<<dim3(N_ / TQ, B_), dim3(256), 0, stream>>>(
        q_hi, q_lo, k_hi, k_lo, v_t, x, gam, out);
}